// Round 14
// baseline (3149.322 us; speedup 1.0000x reference)
//
#include <hip/hip_runtime.h>
#include <hip/hip_bf16.h>

typedef __hip_bfloat16 bf16;
typedef short bf16x8 __attribute__((ext_vector_type(8)));
typedef float f32x4 __attribute__((ext_vector_type(4)));
typedef unsigned long long u64;
typedef unsigned int u32;

#define MFMA16(A, B, C) __builtin_amdgcn_mfma_f32_16x16x32_bf16(A, B, C, 0, 0, 0)

__device__ __forceinline__ float sigf(float x) { return 1.f / (1.f + __expf(-x)); }
__device__ __forceinline__ float tanh_fast(float x) { return 2.f / (1.f + __expf(-2.f * x)) - 1.f; }

// MALL-direct 16B load (two 8B system-relaxed atomics; bypasses L1/L2).
// Used only where cache-dedup is useless (head_k).
__device__ __forceinline__ bf16x8 ld16(const u64* p) {
  u64 lo = __hip_atomic_load(p, __ATOMIC_RELAXED, __HIP_MEMORY_SCOPE_SYSTEM);
  u64 hi = __hip_atomic_load(p + 1, __ATOMIC_RELAXED, __HIP_MEMORY_SCOPE_SYSTEM);
  union { u64 q[2]; bf16x8 v; } u;
  u.q[0] = lo; u.q[1] = hi;
  return u.v;
}

// ---------------- transpose+cast: WT[n][k] = bf16(W[k][n]) ----------------
__global__ __launch_bounds__(256) void transpose_k(const float* __restrict__ W,
                                                   bf16* __restrict__ WT,
                                                   int K, int N) {
  __shared__ bf16 tile[32][33];
  const int n0 = blockIdx.x * 32, k0 = blockIdx.y * 32;
  const int c = threadIdx.x & 31, r0 = threadIdx.x >> 5;
  for (int i = 0; i < 4; ++i) {
    int r = r0 + 8 * i;
    tile[r][c] = __float2bfloat16(W[(long)(k0 + r) * N + (n0 + c)]);
  }
  __syncthreads();
  for (int i = 0; i < 4; ++i) {
    int r = r0 + 8 * i;
    WT[(long)(n0 + r) * K + (k0 + c)] = tile[c][r];
  }
}

// bulk gather of 16 A-chunks from step matrix mat (u64*, per-t base):
// chunk (slice s=4i+q, row m) = 16B at mat + (s*64 + m)*2.
// PLAIN CACHED loads, issued STRICTLY AFTER the sentinel poll confirmed all
// producers (r8 lesson: pre-publish cached reads install stale-poison lines
// in L2). Safe: first-touch is post-publish, buffer_inv at kernel start
// dropped pre-launch stale lines. 16 WGs/XCD dedupe through their XCD L2.
__device__ __forceinline__ void gather16(const u64* __restrict__ mat, int m, int q,
                                         bf16x8* out) {
#pragma unroll
  for (int i = 0; i < 16; ++i) {
    const int s = i * 4 + q;
    out[i] = *(const bf16x8*)(mat + ((long)(s << 6) + m) * 2);
  }
}

// ---------------- fused 2-layer persistent LSTM, sentinel dataflow ----------
// r11 skeleton (proven best): 128 WGs x 256 thr. layer = blk>>6, w = blk&63
// owns h-cols [8w,8w+8). ONE sentinel plane per layer; cached consumer
// gathers; wave-0-only polls; r11 tail (bias in zs-write, one barrier,
// wave-0 eltwise + in-register publish; waves 1-3 run ahead).
// r14 single change (unbundled from r9): layer-1's wave 0 polls s0[t] THEN
// s1[t-1] sequentially before ONE barrier (s1 is near-certainly already set
// by the time s0[t] confirms — layer-0's full step t separates them), then
// BOTH gathers issue back-to-back so h2's L2/MALL fill hides under the 32
// Wi MFMAs instead of being an exposed serial RT after them.
__global__ __launch_bounds__(256, 1) void lstm2_fused_k(
    const float* __restrict__ x,  // [64][512][264] f32
    const bf16* __restrict__ WiT0, const bf16* __restrict__ WhT0,
    const float* __restrict__ bias0,
    const bf16* __restrict__ WiT1, const bf16* __restrict__ WhT1,
    const float* __restrict__ bias1,
    u64* __restrict__ h1D, u64* __restrict__ h2D,
    u32* __restrict__ sent)  // [2][512][64] u32, zeroed
{
  __shared__ short Wis[32 * 520];
  __shared__ short Whs[32 * 520];
  __shared__ float zs[32 * 66];

  const int layer = blockIdx.x >> 6;
  const int w = blockIdx.x & 63;
  const int tid = threadIdx.x;
  const int lane = tid & 63;
  const int wv = tid >> 6;
  const int q = lane >> 4;
  const int r = lane & 15;

  // Drop pre-launch stale clean lines from this CU's L1 / XCD's L2 so all h
  // first-touches fetch current MALL content.
  if (tid == 0) asm volatile("buffer_inv sc0 sc1" ::: "memory");

  const int K_in = layer ? 512 : 256;
  const bf16* WiT = layer ? WiT1 : WiT0;
  const bf16* WhT = layer ? WhT1 : WhT0;
  const float* bias = layer ? bias1 : bias0;
  u32* s0 = sent;                 // layer-0 sentinels
  u32* s1 = sent + 512 * 64;      // layer-1 sentinels
  u64* houtD = layer ? h2D : h1D;
  u32* smy = (layer ? s1 : s0);

  // ---- stage weight slices into LDS (reused all 512 steps) ----
  for (int idx = tid; idx < 32 * 64; idx += 256) {
    const int j = idx >> 6, kc = idx & 63;
    const int zc = (j >> 3) * 512 + w * 8 + (j & 7);
    *(bf16x8*)(Whs + j * 520 + kc * 8) = *(const bf16x8*)(WhT + (long)zc * 512 + kc * 8);
  }
  const int csh = layer ? 6 : 5;
  const int cmask = (1 << csh) - 1;
  for (int idx = tid; idx < (32 << csh); idx += 256) {
    const int j = idx >> csh, kc = idx & cmask;
    const int zc = (j >> 3) * 512 + w * 8 + (j & 7);
    *(bf16x8*)(Wis + j * 520 + kc * 8) = *(const bf16x8*)(WiT + (long)zc * K_in + kc * 8);
  }

  const int m = wv * 16 + r;
  const short* wi0p = Wis + r * 520;
  const short* wi1p = Wis + (16 + r) * 520;
  const short* wh0p = Whs + r * 520;
  const short* wh1p = Whs + (16 + r) * 520;

  // zs-writer bias: this lane's two gate-cols are n0=r (from acc0) and
  // n1=16+r (from acc1); n = g*8 + c -> bias[g*512 + w*8 + c].
  const float brw0 = bias[(r >> 3) * 512 + w * 8 + (r & 7)];
  const float brw1 = bias[(2 + (r >> 3)) * 512 + w * 8 + (r & 7)];
  // wave-0 eltwise state: lane = batch row, 8 h-cols in registers
  float creg8[8] = {0.f, 0.f, 0.f, 0.f, 0.f, 0.f, 0.f, 0.f};

  __syncthreads();

  for (int t = 0; t < 512; ++t) {
    f32x4 acc0 = {0.f, 0.f, 0.f, 0.f};
    f32x4 acc1 = {0.f, 0.f, 0.f, 0.f};

    if (layer == 0) {
      // x-part first: independent of any producer, overlaps others' step t-1
      bf16x8 ax[8];
      const float* row = x + ((long)m * 512 + t) * 264;
#pragma unroll
      for (int i = 0; i < 8; ++i) {
        const float4 f0 = *(const float4*)(row + i * 32 + q * 8);
        const float4 f1 = *(const float4*)(row + i * 32 + q * 8 + 4);
        union { short s[8]; bf16x8 v8; } o;
        o.s[0] = __builtin_bit_cast(short, __float2bfloat16(f0.x));
        o.s[1] = __builtin_bit_cast(short, __float2bfloat16(f0.y));
        o.s[2] = __builtin_bit_cast(short, __float2bfloat16(f0.z));
        o.s[3] = __builtin_bit_cast(short, __float2bfloat16(f0.w));
        o.s[4] = __builtin_bit_cast(short, __float2bfloat16(f1.x));
        o.s[5] = __builtin_bit_cast(short, __float2bfloat16(f1.y));
        o.s[6] = __builtin_bit_cast(short, __float2bfloat16(f1.z));
        o.s[7] = __builtin_bit_cast(short, __float2bfloat16(f1.w));
        ax[i] = o.v8;
      }
#pragma unroll
      for (int i = 0; i < 8; ++i) {
        const int kk = i * 32;
        acc0 = MFMA16(ax[i], *(const bf16x8*)(wi0p + kk + q * 8), acc0);
        acc1 = MFMA16(ax[i], *(const bf16x8*)(wi1p + kk + q * 8), acc1);
      }
      if (t > 0) {
        if (tid < 64) {  // wave 0 polls all 64 producer sentinels of h1[t-1]
          const u32* sp = s0 + (t - 1) * 64 + tid;
          while (__ballot(__hip_atomic_load(sp, __ATOMIC_RELAXED,
                                            __HIP_MEMORY_SCOPE_SYSTEM) != 0) != ~0ull)
            __builtin_amdgcn_s_sleep(2);
        }
        __syncthreads();
        bf16x8 ah[16];
        gather16(h1D + (long)(t - 1) * 8192, m, q, ah);
#pragma unroll
        for (int i = 0; i < 16; ++i) {
          const int kk = i * 32;
          acc0 = MFMA16(ah[i], *(const bf16x8*)(wh0p + kk + q * 8), acc0);
          acc1 = MFMA16(ah[i], *(const bf16x8*)(wh1p + kk + q * 8), acc1);
        }
      }
    } else {
      // r14: wave 0 confirms BOTH dependencies sequentially (s1[t-1] is
      // near-certainly set once s0[t] is — layer-0's full step separates
      // them), ONE barrier, then both gathers issue back-to-back so the
      // h2 fill hides under the Wi MFMAs.
      if (tid < 64) {
        const u32* sp0 = s0 + t * 64 + tid;
        while (__ballot(__hip_atomic_load(sp0, __ATOMIC_RELAXED,
                                          __HIP_MEMORY_SCOPE_SYSTEM) != 0) != ~0ull)
          __builtin_amdgcn_s_sleep(2);
        if (t > 0) {
          const u32* sp1 = s1 + (t - 1) * 64 + tid;
          while (__ballot(__hip_atomic_load(sp1, __ATOMIC_RELAXED,
                                            __HIP_MEMORY_SCOPE_SYSTEM) != 0) != ~0ull)
            __builtin_amdgcn_s_sleep(2);
        }
      }
      __syncthreads();
      bf16x8 ax[16], ah[16];
      gather16(h1D + (long)t * 8192, m, q, ax);
      if (t > 0) gather16(h2D + (long)(t - 1) * 8192, m, q, ah);
#pragma unroll
      for (int i = 0; i < 16; ++i) {
        const int kk = i * 32;
        acc0 = MFMA16(ax[i], *(const bf16x8*)(wi0p + kk + q * 8), acc0);
        acc1 = MFMA16(ax[i], *(const bf16x8*)(wi1p + kk + q * 8), acc1);
      }
      if (t > 0) {
#pragma unroll
        for (int i = 0; i < 16; ++i) {
          const int kk = i * 32;
          acc0 = MFMA16(ah[i], *(const bf16x8*)(wh0p + kk + q * 8), acc0);
          acc1 = MFMA16(ah[i], *(const bf16x8*)(wh1p + kk + q * 8), acc1);
        }
      }
    }

    // D-layout: row(b)=wv*16+q*4+i, col(n)=ntile*16+r  [m89-verified]
    // Bias folded in at write time (n0=r from acc0, n1=16+r from acc1).
    {
      const int brow = wv * 16 + q * 4;
      for (int i = 0; i < 4; ++i) zs[r * 66 + brow + i] = acc0[i] + brw0;
      for (int i = 0; i < 4; ++i) zs[(16 + r) * 66 + brow + i] = acc1[i] + brw1;
    }
    __syncthreads();  // the ONLY per-step barrier in the tail

    // ---- wave-0-only eltwise + in-register publish (r11) ----
    // lane b = batch row; cols c=0..7; zs[n*66+b], n = g*8+c (bias included).
    // Waves 1-3 have already moved on to step t+1 (run-ahead pipeline).
    if (tid < 64) {
      const int b = tid;
      union { u64 qq[2]; short sh[8]; } hp;
#pragma unroll
      for (int c = 0; c < 8; ++c) {
        const float zi = zs[(c) * 66 + b];
        const float zf = zs[(8 + c) * 66 + b];
        const float zg = zs[(16 + c) * 66 + b];
        const float zo = zs[(24 + c) * 66 + b];
        const float cnew = sigf(zf) * creg8[c] + sigf(zi) * tanh_fast(zg);
        const float hnew = sigf(zo) * tanh_fast(cnew);
        creg8[c] = cnew;
        hp.sh[c] = __builtin_bit_cast(short, __float2bfloat16(hnew));
      }
      u64* dst = houtD + (((long)t * 64 + w) * 64 + b) * 2;
      __hip_atomic_store(dst, hp.qq[0], __ATOMIC_RELAXED, __HIP_MEMORY_SCOPE_SYSTEM);
      __hip_atomic_store(dst + 1, hp.qq[1], __ATOMIC_RELAXED, __HIP_MEMORY_SCOPE_SYSTEM);
    }
    if (tid == 0)  // release => vmcnt(0): wave-0's data stores reach MALL first
      __hip_atomic_store(smy + t * 64 + w, 1u, __ATOMIC_RELEASE, __HIP_MEMORY_SCOPE_AGENT);
  }
}

// ---------------- dense head: concat -> 512 -> 256 -> 64 -> sigmoid ----------
__global__ __launch_bounds__(256) void head_k(
    const u64* __restrict__ h2D,  // [512][64][64][8] bf16; reads t=511
    const float* __restrict__ x,
    const float* __restrict__ Wd0, const float* __restrict__ bd0,
    const float* __restrict__ Wd1, const float* __restrict__ bd1,
    const float* __restrict__ Wf, const float* __restrict__ bfv,
    float* __restrict__ out) {
  const int b = blockIdx.x, tid = threadIdx.x;
  __shared__ float in0[520];
  __shared__ float d0s[512];
  __shared__ float d1s[256];
  if (tid < 64) {
    const int s = tid;
    bf16x8 v = ld16(h2D + (((long)511 * 64 + s) * 64 + b) * 2);
    union { bf16x8 v8; short sh[8]; } u;
    u.v8 = v;
    for (int j = 0; j < 8; ++j)
      in0[s * 8 + j] = __bfloat162float(__builtin_bit_cast(bf16, u.sh[j]));
  }
  if (tid < 8) in0[512 + tid] = x[((long)(b * 512 + 511)) * 264 + 256 + tid];
  __syncthreads();
  for (int j = tid; j < 512; j += 256) {
    float a = bd0[j];
    for (int k = 0; k < 520; ++k) a += in0[k] * Wd0[(long)k * 512 + j];
    d0s[j] = fmaxf(a, 0.f);
  }
  __syncthreads();
  if (tid < 256) {
    const int j = tid;
    float a = bd1[j];
    for (int k = 0; k < 512; ++k) a += d0s[k] * Wd1[(long)k * 256 + j];
    d1s[j] = fmaxf(a, 0.f);
  }
  __syncthreads();
  if (tid < 64) {
    const int j = tid;
    float a = bfv[j];
    for (int k = 0; k < 256; ++k) a += d1s[k] * Wf[(long)k * 64 + j];
    out[b * 64 + j] = sigf(a);
  }
}

extern "C" void kernel_launch(void* const* d_in, const int* in_sizes, int n_in,
                              void* d_out, int out_size, void* d_ws, size_t ws_size,
                              hipStream_t stream) {
  const float* x   = (const float*)d_in[0];
  const float* Wi0 = (const float*)d_in[1];
  const float* Wh0 = (const float*)d_in[2];
  const float* b0  = (const float*)d_in[3];
  const float* Wi1 = (const float*)d_in[4];
  const float* Wh1 = (const float*)d_in[5];
  const float* b1  = (const float*)d_in[6];
  const float* Wd0 = (const float*)d_in[7];
  const float* bd0 = (const float*)d_in[8];
  const float* Wd1 = (const float*)d_in[9];
  const float* bd1 = (const float*)d_in[10];
  const float* Wf  = (const float*)d_in[11];
  const float* bf_ = (const float*)d_in[12];
  float* out = (float*)d_out;

  char* ws = (char*)d_ws;
  size_t off = 0;
  auto carve = [&](size_t bytes) {
    void* p = ws + off;
    off += (bytes + 255) & ~(size_t)255;
    return p;
  };
  u32* sent = (u32*)carve((size_t)2 * 512 * 64 * 4);  // 256 KB sentinels
  const size_t zero_bytes = off;
  bf16* WiT0 = (bf16*)carve((size_t)2048 * 256 * 2);
  bf16* WhT0 = (bf16*)carve((size_t)2048 * 512 * 2);
  bf16* WiT1 = (bf16*)carve((size_t)2048 * 512 * 2);
  bf16* WhT1 = (bf16*)carve((size_t)2048 * 512 * 2);
  u64*  h1D  = (u64*)carve((size_t)512 * 64 * 64 * 16);  // 32 MB bf16 history
  u64*  h2D  = (u64*)carve((size_t)512 * 64 * 64 * 16);  // 32 MB bf16 history

  (void)hipMemsetAsync(sent, 0, zero_bytes, stream);

  transpose_k<<<dim3(2048 / 32, 256 / 32), 256, 0, stream>>>(Wi0, WiT0, 256, 2048);
  transpose_k<<<dim3(2048 / 32, 512 / 32), 256, 0, stream>>>(Wh0, WhT0, 512, 2048);
  transpose_k<<<dim3(2048 / 32, 512 / 32), 256, 0, stream>>>(Wi1, WiT1, 512, 2048);
  transpose_k<<<dim3(2048 / 32, 512 / 32), 256, 0, stream>>>(Wh1, WhT1, 512, 2048);

  lstm2_fused_k<<<128, 256, 0, stream>>>(x, WiT0, WhT0, b0, WiT1, WhT1, b1,
                                         h1D, h2D, sent);

  head_k<<<64, 256, 0, stream>>>(h2D, x, Wd0, bd0, Wd1, bd1, Wf, bf_, out);
}

// Round 15
// 2717.298 us; speedup vs baseline: 1.1590x; 1.1590x over previous
//
#include <hip/hip_runtime.h>
#include <hip/hip_bf16.h>

typedef __hip_bfloat16 bf16;
typedef short bf16x8 __attribute__((ext_vector_type(8)));
typedef float f32x4 __attribute__((ext_vector_type(4)));
typedef unsigned long long u64;
typedef unsigned int u32;

#define MFMA16(A, B, C) __builtin_amdgcn_mfma_f32_16x16x32_bf16(A, B, C, 0, 0, 0)

__device__ __forceinline__ float sigf(float x) { return 1.f / (1.f + __expf(-x)); }
__device__ __forceinline__ float tanh_fast(float x) { return 2.f / (1.f + __expf(-2.f * x)) - 1.f; }

// MALL-direct 16B load (two 8B system-relaxed atomics; bypasses L1/L2).
// Used only where cache-dedup is useless (head_k).
__device__ __forceinline__ bf16x8 ld16(const u64* p) {
  u64 lo = __hip_atomic_load(p, __ATOMIC_RELAXED, __HIP_MEMORY_SCOPE_SYSTEM);
  u64 hi = __hip_atomic_load(p + 1, __ATOMIC_RELAXED, __HIP_MEMORY_SCOPE_SYSTEM);
  union { u64 q[2]; bf16x8 v; } u;
  u.q[0] = lo; u.q[1] = hi;
  return u.v;
}

// ---------------- transpose+cast: WT[n][k] = bf16(W[k][n]) ----------------
__global__ __launch_bounds__(256) void transpose_k(const float* __restrict__ W,
                                                   bf16* __restrict__ WT,
                                                   int K, int N) {
  __shared__ bf16 tile[32][33];
  const int n0 = blockIdx.x * 32, k0 = blockIdx.y * 32;
  const int c = threadIdx.x & 31, r0 = threadIdx.x >> 5;
  for (int i = 0; i < 4; ++i) {
    int r = r0 + 8 * i;
    tile[r][c] = __float2bfloat16(W[(long)(k0 + r) * N + (n0 + c)]);
  }
  __syncthreads();
  for (int i = 0; i < 4; ++i) {
    int r = r0 + 8 * i;
    WT[(long)(n0 + r) * K + (k0 + c)] = tile[c][r];
  }
}

// bulk gather of 16 A-chunks from step matrix mat (u64*, per-t base):
// chunk (slice s=4i+q, row m) = 16B at mat + (s*64 + m)*2.
// PLAIN CACHED loads, issued STRICTLY AFTER the sentinel poll confirmed all
// producers (r8 lesson: pre-publish cached reads install stale-poison lines
// in L2). Safe: first-touch is post-publish, buffer_inv at kernel start
// dropped pre-launch stale lines. 16 WGs/XCD dedupe through their XCD L2.
__device__ __forceinline__ void gather16(const u64* __restrict__ mat, int m, int q,
                                         bf16x8* out) {
#pragma unroll
  for (int i = 0; i < 16; ++i) {
    const int s = i * 4 + q;
    out[i] = *(const bf16x8*)(mat + ((long)(s << 6) + m) * 2);
  }
}

// ---------------- fused 2-layer persistent LSTM, sentinel dataflow ----------
// r5 skeleton (proven best): 128 WGs x 256 thr. layer = blk>>6, w = blk&63
// owns h-cols [8w,8w+8). ONE sentinel plane per layer; cached consumer
// gathers; poll placement and publish role exactly r5 (r7/r9/r10/r14
// lessons: poll-when-ready + Wi-work-hides-s1-wait + asymmetric wave-0
// tail are all load-bearing).
// r11 tail: bias folded into zs-write; after ONE zs barrier, wave 0 alone
// does the eltwise for all 64 rows (lane = row, 8 cols in registers,
// c-state in creg8[8]) and publishes DIRECTLY from registers. Waves 1-3
// run ahead into step t+1 right after the zs barrier.
__global__ __launch_bounds__(256, 1) void lstm2_fused_k(
    const float* __restrict__ x,  // [64][512][264] f32
    const bf16* __restrict__ WiT0, const bf16* __restrict__ WhT0,
    const float* __restrict__ bias0,
    const bf16* __restrict__ WiT1, const bf16* __restrict__ WhT1,
    const float* __restrict__ bias1,
    u64* __restrict__ h1D, u64* __restrict__ h2D,
    u32* __restrict__ sent)  // [2][512][64] u32, zeroed
{
  __shared__ short Wis[32 * 520];
  __shared__ short Whs[32 * 520];
  __shared__ float zs[32 * 66];

  const int layer = blockIdx.x >> 6;
  const int w = blockIdx.x & 63;
  const int tid = threadIdx.x;
  const int lane = tid & 63;
  const int wv = tid >> 6;
  const int q = lane >> 4;
  const int r = lane & 15;

  // Drop pre-launch stale clean lines from this CU's L1 / XCD's L2 so all h
  // first-touches fetch current MALL content.
  if (tid == 0) asm volatile("buffer_inv sc0 sc1" ::: "memory");

  const int K_in = layer ? 512 : 256;
  const bf16* WiT = layer ? WiT1 : WiT0;
  const bf16* WhT = layer ? WhT1 : WhT0;
  const float* bias = layer ? bias1 : bias0;
  u32* s0 = sent;                 // layer-0 sentinels
  u32* s1 = sent + 512 * 64;      // layer-1 sentinels
  u64* houtD = layer ? h2D : h1D;
  u32* smy = (layer ? s1 : s0);

  // ---- stage weight slices into LDS (reused all 512 steps) ----
  for (int idx = tid; idx < 32 * 64; idx += 256) {
    const int j = idx >> 6, kc = idx & 63;
    const int zc = (j >> 3) * 512 + w * 8 + (j & 7);
    *(bf16x8*)(Whs + j * 520 + kc * 8) = *(const bf16x8*)(WhT + (long)zc * 512 + kc * 8);
  }
  const int csh = layer ? 6 : 5;
  const int cmask = (1 << csh) - 1;
  for (int idx = tid; idx < (32 << csh); idx += 256) {
    const int j = idx >> csh, kc = idx & cmask;
    const int zc = (j >> 3) * 512 + w * 8 + (j & 7);
    *(bf16x8*)(Wis + j * 520 + kc * 8) = *(const bf16x8*)(WiT + (long)zc * K_in + kc * 8);
  }

  const int m = wv * 16 + r;
  const short* wi0p = Wis + r * 520;
  const short* wi1p = Wis + (16 + r) * 520;
  const short* wh0p = Whs + r * 520;
  const short* wh1p = Whs + (16 + r) * 520;

  // zs-writer bias: this lane's two gate-cols are n0=r (from acc0) and
  // n1=16+r (from acc1); n = g*8 + c -> bias[g*512 + w*8 + c].
  const float brw0 = bias[(r >> 3) * 512 + w * 8 + (r & 7)];
  const float brw1 = bias[(2 + (r >> 3)) * 512 + w * 8 + (r & 7)];
  // wave-0 eltwise state: lane = batch row, 8 h-cols in registers
  float creg8[8] = {0.f, 0.f, 0.f, 0.f, 0.f, 0.f, 0.f, 0.f};

  __syncthreads();

  for (int t = 0; t < 512; ++t) {
    f32x4 acc0 = {0.f, 0.f, 0.f, 0.f};
    f32x4 acc1 = {0.f, 0.f, 0.f, 0.f};

    if (layer == 0) {
      // x-part first: independent of any producer, overlaps others' step t-1
      bf16x8 ax[8];
      const float* row = x + ((long)m * 512 + t) * 264;
#pragma unroll
      for (int i = 0; i < 8; ++i) {
        const float4 f0 = *(const float4*)(row + i * 32 + q * 8);
        const float4 f1 = *(const float4*)(row + i * 32 + q * 8 + 4);
        union { short s[8]; bf16x8 v8; } o;
        o.s[0] = __builtin_bit_cast(short, __float2bfloat16(f0.x));
        o.s[1] = __builtin_bit_cast(short, __float2bfloat16(f0.y));
        o.s[2] = __builtin_bit_cast(short, __float2bfloat16(f0.z));
        o.s[3] = __builtin_bit_cast(short, __float2bfloat16(f0.w));
        o.s[4] = __builtin_bit_cast(short, __float2bfloat16(f1.x));
        o.s[5] = __builtin_bit_cast(short, __float2bfloat16(f1.y));
        o.s[6] = __builtin_bit_cast(short, __float2bfloat16(f1.z));
        o.s[7] = __builtin_bit_cast(short, __float2bfloat16(f1.w));
        ax[i] = o.v8;
      }
#pragma unroll
      for (int i = 0; i < 8; ++i) {
        const int kk = i * 32;
        acc0 = MFMA16(ax[i], *(const bf16x8*)(wi0p + kk + q * 8), acc0);
        acc1 = MFMA16(ax[i], *(const bf16x8*)(wi1p + kk + q * 8), acc1);
      }
      if (t > 0) {
        if (tid < 64) {  // wave 0 polls all 64 producer sentinels of h1[t-1]
          const u32* sp = s0 + (t - 1) * 64 + tid;
          while (__ballot(__hip_atomic_load(sp, __ATOMIC_RELAXED,
                                            __HIP_MEMORY_SCOPE_SYSTEM) != 0) != ~0ull)
            __builtin_amdgcn_s_sleep(2);
        }
        __syncthreads();
        bf16x8 ah[16];
        gather16(h1D + (long)(t - 1) * 8192, m, q, ah);
#pragma unroll
        for (int i = 0; i < 16; ++i) {
          const int kk = i * 32;
          acc0 = MFMA16(ah[i], *(const bf16x8*)(wh0p + kk + q * 8), acc0);
          acc1 = MFMA16(ah[i], *(const bf16x8*)(wh1p + kk + q * 8), acc1);
        }
      }
    } else {
      // x-part = h1[t]; own-layer recurrence last; poll placement = r5
      // (check-when-ready minimizes spin traffic — r10 lesson; the Wi
      // MFMAs hide the true s1[t-1] wait — r14 lesson)
      if (tid < 64) {
        const u32* sp = s0 + t * 64 + tid;
        while (__ballot(__hip_atomic_load(sp, __ATOMIC_RELAXED,
                                          __HIP_MEMORY_SCOPE_SYSTEM) != 0) != ~0ull)
          __builtin_amdgcn_s_sleep(2);
      }
      __syncthreads();
      bf16x8 ax[16];
      gather16(h1D + (long)t * 8192, m, q, ax);
#pragma unroll
      for (int i = 0; i < 16; ++i) {
        const int kk = i * 32;
        acc0 = MFMA16(ax[i], *(const bf16x8*)(wi0p + kk + q * 8), acc0);
        acc1 = MFMA16(ax[i], *(const bf16x8*)(wi1p + kk + q * 8), acc1);
      }
      if (t > 0) {
        if (tid < 64) {
          const u32* sp = s1 + (t - 1) * 64 + tid;
          while (__ballot(__hip_atomic_load(sp, __ATOMIC_RELAXED,
                                            __HIP_MEMORY_SCOPE_SYSTEM) != 0) != ~0ull)
            __builtin_amdgcn_s_sleep(2);
        }
        __syncthreads();
        bf16x8 ah[16];
        gather16(h2D + (long)(t - 1) * 8192, m, q, ah);
#pragma unroll
        for (int i = 0; i < 16; ++i) {
          const int kk = i * 32;
          acc0 = MFMA16(ah[i], *(const bf16x8*)(wh0p + kk + q * 8), acc0);
          acc1 = MFMA16(ah[i], *(const bf16x8*)(wh1p + kk + q * 8), acc1);
        }
      }
    }

    // D-layout: row(b)=wv*16+q*4+i, col(n)=ntile*16+r  [m89-verified]
    // Bias folded in at write time (n0=r from acc0, n1=16+r from acc1).
    {
      const int brow = wv * 16 + q * 4;
      for (int i = 0; i < 4; ++i) zs[r * 66 + brow + i] = acc0[i] + brw0;
      for (int i = 0; i < 4; ++i) zs[(16 + r) * 66 + brow + i] = acc1[i] + brw1;
    }
    __syncthreads();  // the ONLY per-step barrier in the tail

    // ---- wave-0-only eltwise + in-register publish ----
    // lane b = batch row; cols c=0..7; zs[n*66+b], n = g*8+c (bias included).
    // zs reads are stride-1 across lanes -> 2 lanes/bank, conflict-free.
    // Waves 1-3 have already moved on to step t+1 (run-ahead pipeline).
    if (tid < 64) {
      const int b = tid;
      union { u64 qq[2]; short sh[8]; } hp;
#pragma unroll
      for (int c = 0; c < 8; ++c) {
        const float zi = zs[(c) * 66 + b];
        const float zf = zs[(8 + c) * 66 + b];
        const float zg = zs[(16 + c) * 66 + b];
        const float zo = zs[(24 + c) * 66 + b];
        const float cnew = sigf(zf) * creg8[c] + sigf(zi) * tanh_fast(zg);
        const float hnew = sigf(zo) * tanh_fast(cnew);
        creg8[c] = cnew;
        hp.sh[c] = __builtin_bit_cast(short, __float2bfloat16(hnew));
      }
      u64* dst = houtD + (((long)t * 64 + w) * 64 + b) * 2;
      __hip_atomic_store(dst, hp.qq[0], __ATOMIC_RELAXED, __HIP_MEMORY_SCOPE_SYSTEM);
      __hip_atomic_store(dst + 1, hp.qq[1], __ATOMIC_RELAXED, __HIP_MEMORY_SCOPE_SYSTEM);
    }
    if (tid == 0)  // release => vmcnt(0): wave-0's data stores reach MALL first
      __hip_atomic_store(smy + t * 64 + w, 1u, __ATOMIC_RELEASE, __HIP_MEMORY_SCOPE_AGENT);
  }
}

// ---------------- dense head: concat -> 512 -> 256 -> 64 -> sigmoid ----------
__global__ __launch_bounds__(256) void head_k(
    const u64* __restrict__ h2D,  // [512][64][64][8] bf16; reads t=511
    const float* __restrict__ x,
    const float* __restrict__ Wd0, const float* __restrict__ bd0,
    const float* __restrict__ Wd1, const float* __restrict__ bd1,
    const float* __restrict__ Wf, const float* __restrict__ bfv,
    float* __restrict__ out) {
  const int b = blockIdx.x, tid = threadIdx.x;
  __shared__ float in0[520];
  __shared__ float d0s[512];
  __shared__ float d1s[256];
  if (tid < 64) {
    const int s = tid;
    bf16x8 v = ld16(h2D + (((long)511 * 64 + s) * 64 + b) * 2);
    union { bf16x8 v8; short sh[8]; } u;
    u.v8 = v;
    for (int j = 0; j < 8; ++j)
      in0[s * 8 + j] = __bfloat162float(__builtin_bit_cast(bf16, u.sh[j]));
  }
  if (tid < 8) in0[512 + tid] = x[((long)(b * 512 + 511)) * 264 + 256 + tid];
  __syncthreads();
  for (int j = tid; j < 512; j += 256) {
    float a = bd0[j];
    for (int k = 0; k < 520; ++k) a += in0[k] * Wd0[(long)k * 512 + j];
    d0s[j] = fmaxf(a, 0.f);
  }
  __syncthreads();
  if (tid < 256) {
    const int j = tid;
    float a = bd1[j];
    for (int k = 0; k < 512; ++k) a += d0s[k] * Wd1[(long)k * 256 + j];
    d1s[j] = fmaxf(a, 0.f);
  }
  __syncthreads();
  if (tid < 64) {
    const int j = tid;
    float a = bfv[j];
    for (int k = 0; k < 256; ++k) a += d1s[k] * Wf[(long)k * 64 + j];
    out[b * 64 + j] = sigf(a);
  }
}

extern "C" void kernel_launch(void* const* d_in, const int* in_sizes, int n_in,
                              void* d_out, int out_size, void* d_ws, size_t ws_size,
                              hipStream_t stream) {
  const float* x   = (const float*)d_in[0];
  const float* Wi0 = (const float*)d_in[1];
  const float* Wh0 = (const float*)d_in[2];
  const float* b0  = (const float*)d_in[3];
  const float* Wi1 = (const float*)d_in[4];
  const float* Wh1 = (const float*)d_in[5];
  const float* b1  = (const float*)d_in[6];
  const float* Wd0 = (const float*)d_in[7];
  const float* bd0 = (const float*)d_in[8];
  const float* Wd1 = (const float*)d_in[9];
  const float* bd1 = (const float*)d_in[10];
  const float* Wf  = (const float*)d_in[11];
  const float* bf_ = (const float*)d_in[12];
  float* out = (float*)d_out;

  char* ws = (char*)d_ws;
  size_t off = 0;
  auto carve = [&](size_t bytes) {
    void* p = ws + off;
    off += (bytes + 255) & ~(size_t)255;
    return p;
  };
  u32* sent = (u32*)carve((size_t)2 * 512 * 64 * 4);  // 256 KB sentinels
  const size_t zero_bytes = off;
  bf16* WiT0 = (bf16*)carve((size_t)2048 * 256 * 2);
  bf16* WhT0 = (bf16*)carve((size_t)2048 * 512 * 2);
  bf16* WiT1 = (bf16*)carve((size_t)2048 * 512 * 2);
  bf16* WhT1 = (bf16*)carve((size_t)2048 * 512 * 2);
  u64*  h1D  = (u64*)carve((size_t)512 * 64 * 64 * 16);  // 32 MB bf16 history
  u64*  h2D  = (u64*)carve((size_t)512 * 64 * 64 * 16);  // 32 MB bf16 history

  (void)hipMemsetAsync(sent, 0, zero_bytes, stream);

  transpose_k<<<dim3(2048 / 32, 256 / 32), 256, 0, stream>>>(Wi0, WiT0, 256, 2048);
  transpose_k<<<dim3(2048 / 32, 512 / 32), 256, 0, stream>>>(Wh0, WhT0, 512, 2048);
  transpose_k<<<dim3(2048 / 32, 512 / 32), 256, 0, stream>>>(Wi1, WiT1, 512, 2048);
  transpose_k<<<dim3(2048 / 32, 512 / 32), 256, 0, stream>>>(Wh1, WhT1, 512, 2048);

  lstm2_fused_k<<<128, 256, 0, stream>>>(x, WiT0, WhT0, b0, WiT1, WhT1, b1,
                                         h1D, h2D, sent);

  head_k<<<64, 256, 0, stream>>>(h2D, x, Wd0, bd0, Wd1, bd1, Wf, bf_, out);
}